// Round 7
// baseline (1348.341 us; speedup 1.0000x reference)
//
#include <hip/hip_runtime.h>
#include <math.h>

#define SEQT 1024
#define NTOK 2048
#define HIDN 512
#define NHD 8
#define HDIM 64
#define KTSN 4

typedef float v2f __attribute__((ext_vector_type(2)));

__device__ __forceinline__ v2f pk_fma2(v2f a, v2f b, v2f c) {
#if __has_builtin(__builtin_elementwise_fma)
  return __builtin_elementwise_fma(a, b, c);
#else
  v2f r; r.x = fmaf(a.x, b.x, c.x); r.y = fmaf(a.y, b.y, c.y); return r;
#endif
}

__device__ __forceinline__ float wred(float v) {
#pragma unroll
  for (int off = 32; off; off >>= 1) v += __shfl_xor(v, off, 64);
  return v;
}

// rotation-allreduce within rows of 16 via DPP (VALU-speed), then 2 shuffles
template <int CTRL>
__device__ __forceinline__ float rra(float v) {
  return v + __int_as_float(__builtin_amdgcn_update_dpp(
                 0, __float_as_int(v), CTRL, 0xf, 0xf, true));
}
__device__ __forceinline__ float wsum64(float v) {
  v = rra<0x121>(v);  // row_ror:1
  v = rra<0x122>(v);  // row_ror:2
  v = rra<0x124>(v);  // row_ror:4
  v = rra<0x128>(v);  // row_ror:8  -> each lane has its 16-row sum
  v += __shfl_xor(v, 16, 64);
  v += __shfl_xor(v, 32, 64);
  return v;
}

// ---------------- K1: input RMSNorm (one block per row) ----------------
__global__ __launch_bounds__(256) void k_rmsnorm_in(
    const float* __restrict__ x, const float* __restrict__ w, float* __restrict__ xn) {
  int m = blockIdx.x;
  int tid = threadIdx.x;
  const float* row = x + (size_t)m * HIDN;
  float2 v = *(const float2*)(row + tid * 2);
  float ss = wred(v.x * v.x + v.y * v.y);
  __shared__ float red[4];
  int lane = tid & 63, wv = tid >> 6;
  if (lane == 0) red[wv] = ss;
  __syncthreads();
  float tot = red[0] + red[1] + red[2] + red[3];
  float inv = rsqrtf(tot * (1.0f / HIDN) + 1e-5f);
  float2 wv2 = *(const float2*)(w + tid * 2);
  float2 o;
  o.x = v.x * inv * wv2.x;
  o.y = v.y * inv * wv2.y;
  *(float2*)(xn + (size_t)m * HIDN + tid * 2) = o;
}

// ---------------- K2: C[m][n] = sum_k A[m][k]*B[n][k]  (M=2048, K=512) ----------------
__global__ __launch_bounds__(256) void k_gemm_nt(
    const float* __restrict__ A, const float* __restrict__ B, float* __restrict__ C, int N) {
  __shared__ __align__(16) float As[32][68];
  __shared__ __align__(16) float Bs[32][68];
  int tid = threadIdx.x;
  int m0 = blockIdx.x * 64, n0 = blockIdx.y * 64;
  int tm = tid >> 4, tn = tid & 15;
  float acc[4][4] = {};
  int rr = tid >> 2, cc = (tid & 3) * 8;
  for (int k0 = 0; k0 < HIDN; k0 += 32) {
    const float* s0 = A + (size_t)(m0 + rr) * HIDN + k0 + cc;
    float4 a0 = *(const float4*)s0;
    float4 a1 = *(const float4*)(s0 + 4);
    As[cc + 0][rr] = a0.x; As[cc + 1][rr] = a0.y; As[cc + 2][rr] = a0.z; As[cc + 3][rr] = a0.w;
    As[cc + 4][rr] = a1.x; As[cc + 5][rr] = a1.y; As[cc + 6][rr] = a1.z; As[cc + 7][rr] = a1.w;
    int bn = n0 + rr;
    float4 b0 = make_float4(0.f, 0.f, 0.f, 0.f), b1 = make_float4(0.f, 0.f, 0.f, 0.f);
    if (bn < N) {
      const float* s1 = B + (size_t)bn * HIDN + k0 + cc;
      b0 = *(const float4*)s1;
      b1 = *(const float4*)(s1 + 4);
    }
    Bs[cc + 0][rr] = b0.x; Bs[cc + 1][rr] = b0.y; Bs[cc + 2][rr] = b0.z; Bs[cc + 3][rr] = b0.w;
    Bs[cc + 4][rr] = b1.x; Bs[cc + 5][rr] = b1.y; Bs[cc + 6][rr] = b1.z; Bs[cc + 7][rr] = b1.w;
    __syncthreads();
#pragma unroll
    for (int kk = 0; kk < 32; ++kk) {
      float4 a4 = *(const float4*)&As[kk][tm * 4];
      float4 b4 = *(const float4*)&Bs[kk][tn * 4];
      float aa[4] = {a4.x, a4.y, a4.z, a4.w};
      float bb[4] = {b4.x, b4.y, b4.z, b4.w};
#pragma unroll
      for (int i = 0; i < 4; ++i)
#pragma unroll
        for (int j = 0; j < 4; ++j) acc[i][j] += aa[i] * bb[j];
    }
    __syncthreads();
  }
#pragma unroll
  for (int i = 0; i < 4; ++i) {
    int mr = m0 + tm * 4 + i;
#pragma unroll
    for (int j = 0; j < 4; ++j) {
      int nc = n0 + tn * 4 + j;
      if (nc < N) C[(size_t)mr * N + nc] = acc[i][j];
    }
  }
}

// ---------------- K3a: rope cos/sin table [t][j] ----------------
__global__ __launch_bounds__(256) void k_rope_table(float2* __restrict__ tab) {
  int idx = blockIdx.x * 256 + threadIdx.x;  // 1024*32
  int t = idx >> 5, j = idx & 31;
  float invf = (float)exp2(-(double)j * (13.287712379549449 / 32.0));  // 10000^(-j/32)
  float ang = (float)t * invf;                                         // fp32, matches ref
  double s, c;
  sincos((double)ang, &s, &c);
  tab[idx] = make_float2((float)c, (float)s);
}

// ---------------- K3b: rope(q,k), rmsnorm(k), rmsnorm(v), alpha, mix; transpose ----------------
__global__ __launch_bounds__(256) void k_postproc(
    const float* __restrict__ q_in, const float* __restrict__ k_in, const float* __restrict__ v_in,
    const float* __restrict__ a_pre, const float* __restrict__ m_pre,
    const float* __restrict__ ab, const float* __restrict__ mb,
    const float* __restrict__ kn_w, const float* __restrict__ vn_w,
    const float2* __restrict__ tab,
    float* __restrict__ qh, float* __restrict__ kh, float* __restrict__ vh,
    float* __restrict__ av, float* __restrict__ mv) {
  int wid = blockIdx.x * 4 + (threadIdx.x >> 6);  // one wave per (b,t,h)
  int lane = threadIdx.x & 63;
  int b = wid >> 13;
  int rem = wid & 8191;
  int t = rem >> 3;
  int h = rem & 7;
  size_t src = (size_t)(b * SEQT + t) * HIDN + h * HDIM + lane;
  float qv = q_in[src], kv = k_in[src], vv = v_in[src];
  float2 cs = tab[t * 32 + (lane & 31)];
  float qpart = __shfl_xor(qv, 32, 64);
  float kpart = __shfl_xor(kv, 32, 64);
  float qr = (lane < 32) ? (qv * cs.x - qpart * cs.y) : (qpart * cs.y + qv * cs.x);
  float kr = (lane < 32) ? (kv * cs.x - kpart * cs.y) : (kpart * cs.y + kv * cs.x);
  float kss = wred(kr * kr);
  float kn = kr * rsqrtf(kss * (1.0f / HDIM) + 1e-5f) * kn_w[lane];
  float vss = wred(vv * vv);
  float vn = vv * rsqrtf(vss * (1.0f / HDIM) + 1e-5f) * vn_w[lane];
  size_t dst = ((size_t)(b * NHD + h) * SEQT + t) * HDIM + lane;
  qh[dst] = qr;
  kh[dst] = kn;
  vh[dst] = vn;
  if (lane < 4) {
    int col = h * 4 + lane;
    float pa = a_pre[(size_t)(b * SEQT + t) * 32 + col] + ab[col];
    float al = 1.0f / (1.0f + expf(-pa));
    al = fminf(fmaxf(al, 1e-4f), 0.9995f);
    float pm = m_pre[(size_t)(b * SEQT + t) * 32 + col] + mb[col];
    float mx = pm;
    mx = fmaxf(mx, __shfl_xor(mx, 1, 64));
    mx = fmaxf(mx, __shfl_xor(mx, 2, 64));
    float e = expf(pm - mx);
    float sum = e;
    sum += __shfl_xor(sum, 1, 64);
    sum += __shfl_xor(sum, 2, 64);
    size_t adst = ((size_t)(b * NHD + h) * KTSN + lane) * SEQT + t;
    av[adst] = al;
    mv[adst] = e / sum;
  }
}

// ---------------- K4: sequential scan, ONE WAVE per (b,h,kt) cell ----------------
// h-state = 32 NAMED v2f vars (pure IR packed math -> v_pk_fma_f32, NO inline
// asm so SROA promotes; r6 proved asm was the spill trigger). 4-buffer LDS
// pipeline: iter T reads kq[T&3] (written 2 iters ago), writes kq[(T+2)&3].
// Global prefetch distance 3. Unroll-4 makes all parities compile-time.
#define G16(X) \
  X(0) X(1) X(2) X(3) X(4) X(5) X(6) X(7) \
  X(8) X(9) X(10) X(11) X(12) X(13) X(14) X(15)

#define DECLH(g) v2f hA##g = {0.f, 0.f}; v2f hB##g = {0.f, 0.f};

#define UPDH(g)                                          \
  {                                                      \
    float4 kf = kvec[g];                                 \
    v2f k0 = {kf.x, kf.y};                               \
    v2f k1 = {kf.z, kf.w};                               \
    hA##g = pk_fma2(hA##g, ag2, k0 * vem2);              \
    hB##g = pk_fma2(hB##g, ag2, k1 * vem2);              \
    sqa = pk_fma2(hA##g, hA##g, sqa);                    \
    sqb = pk_fma2(hB##g, hB##g, sqb);                    \
  }

#define YUPH(g)                                          \
  {                                                      \
    float4 qf = qvec[g];                                 \
    v2f q0 = {qf.x, qf.y};                               \
    v2f q1 = {qf.z, qf.w};                               \
    ya = pk_fma2(q0, hA##g, ya);                         \
    yb = pk_fma2(q1, hB##g, yb);                         \
  }

#define SCAN_BODY(T, RP, WP)                                              \
  {                                                                       \
    const float4* kvec = (const float4*)&kq[RP][0][0];                    \
    const float4* qvec = (const float4*)&kq[RP][1][0];                    \
    float ag = aC * gprev;   /* deferred norm scale folded into alpha */  \
    float vem = vC * mC;     /* mask folded into v */                     \
    v2f ag2 = {ag, ag};                                                   \
    v2f vem2 = {vem, vem};                                                \
    v2f sqa = {0.f, 0.f}, sqb = {0.f, 0.f};                               \
    G16(UPDH)                                                             \
    int t3 = (T) + 3;                                                     \
    if (t3 > SEQT - 1) t3 = SEQT - 1;                                     \
    float kN = kp[(size_t)t3 * HDIM + lane];                              \
    float qN = qp[(size_t)t3 * HDIM + lane];                              \
    float vN = vp[(size_t)t3 * HDIM + lane];                              \
    float aN = ap[t3];                                                    \
    float mxN = mp[t3];                                                   \
    float mN = (float)mk[t3];                                             \
    v2f sqs = sqa + sqb;                                                  \
    float sq = wsum64(sqs.x + sqs.y);                                     \
    v2f ya = {0.f, 0.f}, yb = {0.f, 0.f};                                 \
    G16(YUPH)                                                             \
    float g = fminf(16.0f / (sqrtf(sq) + 1e-6f), 1.0f); /* c=sqrt(64)*2 */\
    v2f ys = ya + yb;                                                     \
    ypo[(size_t)(T) * HIDN] = (mxC * g) * (ys.x + ys.y);                  \
    gprev = g;                                                            \
    kq[WP][0][lane] = kA;                                                 \
    kq[WP][1][lane] = qA;                                                 \
    kA = kN; qA = qN;                                                     \
    vC = vD; vD = vE; vE = vN;                                            \
    aC = aD; aD = aE; aE = aN;                                            \
    mxC = mxD; mxD = mxE; mxE = mxN;                                      \
    mC = mD; mD = mE; mE = mN;                                            \
  }

__global__ __launch_bounds__(64, 1) __attribute__((amdgpu_waves_per_eu(1)))
void k_scan(
    const float* __restrict__ qh, const float* __restrict__ kh, const float* __restrict__ vh,
    const float* __restrict__ av, const float* __restrict__ mv, const int* __restrict__ mask,
    float* __restrict__ y0p, float* __restrict__ y1p, float* __restrict__ y2p,
    float* __restrict__ y3p) {
  int c = blockIdx.x;  // (b*NH+h)*KTS + kt
  int kt = c & 3;
  int bh = c >> 2;
  int b = bh >> 3;
  int h = bh & 7;
  int lane = threadIdx.x;  // 0..63, = e

  const float* kp = kh + (size_t)bh * SEQT * HDIM;
  const float* qp = qh + (size_t)bh * SEQT * HDIM;
  const float* vp = vh + (size_t)bh * SEQT * HDIM;
  const float* ap = av + (size_t)c * SEQT;
  const float* mp = mv + (size_t)c * SEQT;
  const int* mk = mask + (size_t)b * SEQT;
  float* ysel = (kt == 0) ? y0p : (kt == 1) ? y1p : (kt == 2) ? y2p : y3p;
  float* ypo = ysel + (size_t)(b * SEQT) * HIDN + h * HDIM + lane;

  __shared__ __align__(16) float kq[4][2][64];  // [buf][k|q][d] - 2KB

  G16(DECLH)  // hA0..hB15 = 32 v2f = 64 floats, all zero
  float gprev = 1.0f;

  // prologue (single wave: no barriers): stage steps 0,1 into LDS; step 2 in regs
  kq[0][0][lane] = kp[lane];
  kq[0][1][lane] = qp[lane];
  kq[1][0][lane] = kp[HDIM + lane];
  kq[1][1][lane] = qp[HDIM + lane];
  float kA = kp[2 * HDIM + lane], qA = qp[2 * HDIM + lane];
  float vC = vp[lane], vD = vp[HDIM + lane], vE = vp[2 * HDIM + lane];
  float aC = ap[0], aD = ap[1], aE = ap[2];
  float mxC = mp[0], mxD = mp[1], mxE = mp[2];
  float mC = (float)mk[0], mD = (float)mk[1], mE = (float)mk[2];

  for (int t = 0; t < SEQT; t += 4) {
    SCAN_BODY(t + 0, 0, 2)
    SCAN_BODY(t + 1, 1, 3)
    SCAN_BODY(t + 2, 2, 0)
    SCAN_BODY(t + 3, 3, 1)
  }
}

// ---------------- K5: r = x + (sum_kt y) @ oW^T + ob ----------------
__global__ __launch_bounds__(256) void k_gemm_out(
    const float* __restrict__ y0, const float* __restrict__ y1,
    const float* __restrict__ y2, const float* __restrict__ y3,
    const float* __restrict__ oW, const float* __restrict__ ob,
    const float* __restrict__ x, float* __restrict__ r) {
  __shared__ __align__(16) float As[32][68];
  __shared__ __align__(16) float Bs[32][68];
  int tid = threadIdx.x;
  int m0 = blockIdx.x * 64, n0 = blockIdx.y * 64;
  int tm = tid >> 4, tn = tid & 15;
  float acc[4][4] = {};
  int rr = tid >> 2, cc = (tid & 3) * 8;
  for (int k0 = 0; k0 < HIDN; k0 += 32) {
    size_t aoff = (size_t)(m0 + rr) * HIDN + k0 + cc;
#pragma unroll
    for (int half = 0; half < 2; ++half) {
      size_t sh = aoff + half * 4;
      float4 p0 = *(const float4*)(y0 + sh);
      float4 p1 = *(const float4*)(y1 + sh);
      float4 p2 = *(const float4*)(y2 + sh);
      float4 p3 = *(const float4*)(y3 + sh);
      int cbase = cc + half * 4;
      As[cbase + 0][rr] = p0.x + p1.x + p2.x + p3.x;
      As[cbase + 1][rr] = p0.y + p1.y + p2.y + p3.y;
      As[cbase + 2][rr] = p0.z + p1.z + p2.z + p3.z;
      As[cbase + 3][rr] = p0.w + p1.w + p2.w + p3.w;
    }
    const float* s1 = oW + (size_t)(n0 + rr) * HIDN + k0 + cc;
    float4 b0 = *(const float4*)s1;
    float4 b1 = *(const float4*)(s1 + 4);
    Bs[cc + 0][rr] = b0.x; Bs[cc + 1][rr] = b0.y; Bs[cc + 2][rr] = b0.z; Bs[cc + 3][rr] = b0.w;
    Bs[cc + 4][rr] = b1.x; Bs[cc + 5][rr] = b1.y; Bs[cc + 6][rr] = b1.z; Bs[cc + 7][rr] = b1.w;
    __syncthreads();
#pragma unroll
    for (int kk = 0; kk < 32; ++kk) {
      float4 a4 = *(const float4*)&As[kk][tm * 4];
      float4 b4 = *(const float4*)&Bs[kk][tn * 4];
      float aa[4] = {a4.x, a4.y, a4.z, a4.w};
      float bb[4] = {b4.x, b4.y, b4.z, b4.w};
#pragma unroll
      for (int i = 0; i < 4; ++i)
#pragma unroll
        for (int j = 0; j < 4; ++j) acc[i][j] += aa[i] * bb[j];
    }
    __syncthreads();
  }
#pragma unroll
  for (int i = 0; i < 4; ++i) {
    int mr = m0 + tm * 4 + i;
#pragma unroll
    for (int j = 0; j < 4; ++j) {
      int nc = n0 + tn * 4 + j;
      r[(size_t)mr * HIDN + nc] = x[(size_t)mr * HIDN + nc] + acc[i][j] + ob[nc];
    }
  }
}

// ---------------- K6: LayerNorm -> out ----------------
__global__ __launch_bounds__(256) void k_layernorm(
    const float* __restrict__ r, const float* __restrict__ w, const float* __restrict__ bb,
    float* __restrict__ out) {
  int m = blockIdx.x;
  int tid = threadIdx.x;
  const float* row = r + (size_t)m * HIDN;
  float2 v = *(const float2*)(row + tid * 2);
  float s = wred(v.x + v.y);
  float ss = wred(v.x * v.x + v.y * v.y);
  __shared__ float r1[4], r2[4];
  int lane = tid & 63, wv = tid >> 6;
  if (lane == 0) {
    r1[wv] = s;
    r2[wv] = ss;
  }
  __syncthreads();
  float S = r1[0] + r1[1] + r1[2] + r1[3];
  float SS = r2[0] + r2[1] + r2[2] + r2[3];
  float mu = S * (1.0f / HIDN);
  float var = SS * (1.0f / HIDN) - mu * mu;
  float inv = rsqrtf(var + 1e-5f);
  float2 w2 = *(const float2*)(w + tid * 2);
  float2 b2 = *(const float2*)(bb + tid * 2);
  float2 o;
  o.x = (v.x - mu) * inv * w2.x + b2.x;
  o.y = (v.y - mu) * inv * w2.y + b2.y;
  *(float2*)(out + (size_t)m * HIDN + tid * 2) = o;
}

// ---------------- launch ----------------
extern "C" void kernel_launch(void* const* d_in, const int* in_sizes, int n_in,
                              void* d_out, int out_size, void* d_ws, size_t ws_size,
                              hipStream_t stream) {
  const float* x = (const float*)d_in[0];
  const float* in_w = (const float*)d_in[1];
  const float* qW = (const float*)d_in[2];
  const float* kW = (const float*)d_in[3];
  const float* vW = (const float*)d_in[4];
  const float* aW = (const float*)d_in[5];
  const float* ab = (const float*)d_in[6];
  const float* mW = (const float*)d_in[7];
  const float* mb = (const float*)d_in[8];
  const float* oW = (const float*)d_in[9];
  const float* ob = (const float*)d_in[10];
  const float* kn_w = (const float*)d_in[11];
  const float* vn_w = (const float*)d_in[12];
  const float* ln_w = (const float*)d_in[13];
  const float* ln_b = (const float*)d_in[14];
  const int* mask = (const int*)d_in[15];

  float* ws = (float*)d_ws;
  // Layout (floats). No live overlap:
  //   xn    [0        , 1048576 )  dead after 5 GEMMs -> reused as rr
  //   qb    [1048576  , 2097152 )  dead after postproc -> reused as y0
  //   kb    [2097152  , 3145728 )  dead after postproc -> reused as y1
  //   vb    [3145728  , 4194304 )  dead after postproc -> reused as y2
  //   apre  [4194304  , 4259840 )
  //   mpre  [4259840  , 4325376 )
  //   tab   [4325376  , 4390912 )
  //   qh    [4390912  , 5439488 )
  //   kh    [5439488  , 6488064 )
  //   vh    [6488064  , 7536640 )
  //   avv   [7536640  , 7602176 )
  //   mvv   [7602176  , 7667712 )
  //   y3    [7667712  , 8716288 )   total ~34.9 MB
  float* xn = ws + 0;
  float* qb = ws + 1048576;
  float* kb = ws + 2097152;
  float* vb = ws + 3145728;
  float* apre = ws + 4194304;
  float* mpre = ws + 4259840;
  float2* tab = (float2*)(ws + 4325376);
  float* qh = ws + 4390912;
  float* kh = ws + 5439488;
  float* vh = ws + 6488064;
  float* avv = ws + 7536640;
  float* mvv = ws + 7602176;
  float* y3 = ws + 7667712;
  float* y0 = qb;
  float* y1 = kb;
  float* y2 = vb;
  float* rr = xn;

  k_rmsnorm_in<<<NTOK, 256, 0, stream>>>(x, in_w, xn);
  k_rope_table<<<128, 256, 0, stream>>>(tab);
  dim3 gBig(32, 8);
  k_gemm_nt<<<gBig, 256, 0, stream>>>(xn, qW, qb, 512);
  k_gemm_nt<<<gBig, 256, 0, stream>>>(xn, kW, kb, 512);
  k_gemm_nt<<<gBig, 256, 0, stream>>>(xn, vW, vb, 512);
  dim3 gSmall(32, 1);
  k_gemm_nt<<<gSmall, 256, 0, stream>>>(xn, aW, apre, 32);
  k_gemm_nt<<<gSmall, 256, 0, stream>>>(xn, mW, mpre, 32);
  k_postproc<<<4096, 256, 0, stream>>>(qb, kb, vb, apre, mpre, ab, mb, kn_w, vn_w, tab,
                                       qh, kh, vh, avv, mvv);
  k_scan<<<64, 64, 0, stream>>>(qh, kh, vh, avv, mvv, mask, y0, y1, y2, y3);
  k_gemm_out<<<gBig, 256, 0, stream>>>(y0, y1, y2, y3, oW, ob, x, rr);
  k_layernorm<<<NTOK, 256, 0, stream>>>(rr, ln_w, ln_b, (float*)d_out);
  (void)in_sizes; (void)n_in; (void)out_size; (void)ws_size;
}

// Round 8
// 1334.643 us; speedup vs baseline: 1.0103x; 1.0103x over previous
//
#include <hip/hip_runtime.h>
#include <math.h>

#define SEQT 1024
#define NTOK 2048
#define HIDN 512
#define NHD 8
#define HDIM 64
#define KTSN 4

__device__ __forceinline__ float wred(float v) {
#pragma unroll
  for (int off = 32; off; off >>= 1) v += __shfl_xor(v, off, 64);
  return v;
}

// rotation-allreduce within rows of 16 via DPP (VALU-speed)
template <int CTRL>
__device__ __forceinline__ float rra(float v) {
  return v + __int_as_float(__builtin_amdgcn_update_dpp(
                 0, __float_as_int(v), CTRL, 0xf, 0xf, true));
}
__device__ __forceinline__ float rlane(float v, int l) {
  return __int_as_float(__builtin_amdgcn_readlane(__float_as_int(v), l));
}
// full-wave sum: 4 DPP row_rors (row sums) + 4 readlanes + scalar adds.
// Avoids ds_bpermute (LDS-pipe latency) on the serial g-chain.
__device__ __forceinline__ float wsum64_fast(float v) {
  v = rra<0x121>(v);  // row_ror:1
  v = rra<0x122>(v);  // row_ror:2
  v = rra<0x124>(v);  // row_ror:4
  v = rra<0x128>(v);  // row_ror:8  -> each lane has its 16-lane row sum
  return (rlane(v, 0) + rlane(v, 16)) + (rlane(v, 32) + rlane(v, 48));
}

// ---------------- K1: input RMSNorm (one block per row) ----------------
__global__ __launch_bounds__(256) void k_rmsnorm_in(
    const float* __restrict__ x, const float* __restrict__ w, float* __restrict__ xn) {
  int m = blockIdx.x;
  int tid = threadIdx.x;
  const float* row = x + (size_t)m * HIDN;
  float2 v = *(const float2*)(row + tid * 2);
  float ss = wred(v.x * v.x + v.y * v.y);
  __shared__ float red[4];
  int lane = tid & 63, wv = tid >> 6;
  if (lane == 0) red[wv] = ss;
  __syncthreads();
  float tot = red[0] + red[1] + red[2] + red[3];
  float inv = rsqrtf(tot * (1.0f / HIDN) + 1e-5f);
  float2 wv2 = *(const float2*)(w + tid * 2);
  float2 o;
  o.x = v.x * inv * wv2.x;
  o.y = v.y * inv * wv2.y;
  *(float2*)(xn + (size_t)m * HIDN + tid * 2) = o;
}

// ---------------- K2: C[m][n] = sum_k A[m][k]*B[n][k]  (M=2048, K=512) ----------------
__global__ __launch_bounds__(256) void k_gemm_nt(
    const float* __restrict__ A, const float* __restrict__ B, float* __restrict__ C, int N) {
  __shared__ __align__(16) float As[32][68];
  __shared__ __align__(16) float Bs[32][68];
  int tid = threadIdx.x;
  int m0 = blockIdx.x * 64, n0 = blockIdx.y * 64;
  int tm = tid >> 4, tn = tid & 15;
  float acc[4][4] = {};
  int rr = tid >> 2, cc = (tid & 3) * 8;
  for (int k0 = 0; k0 < HIDN; k0 += 32) {
    const float* s0 = A + (size_t)(m0 + rr) * HIDN + k0 + cc;
    float4 a0 = *(const float4*)s0;
    float4 a1 = *(const float4*)(s0 + 4);
    As[cc + 0][rr] = a0.x; As[cc + 1][rr] = a0.y; As[cc + 2][rr] = a0.z; As[cc + 3][rr] = a0.w;
    As[cc + 4][rr] = a1.x; As[cc + 5][rr] = a1.y; As[cc + 6][rr] = a1.z; As[cc + 7][rr] = a1.w;
    int bn = n0 + rr;
    float4 b0 = make_float4(0.f, 0.f, 0.f, 0.f), b1 = make_float4(0.f, 0.f, 0.f, 0.f);
    if (bn < N) {
      const float* s1 = B + (size_t)bn * HIDN + k0 + cc;
      b0 = *(const float4*)s1;
      b1 = *(const float4*)(s1 + 4);
    }
    Bs[cc + 0][rr] = b0.x; Bs[cc + 1][rr] = b0.y; Bs[cc + 2][rr] = b0.z; Bs[cc + 3][rr] = b0.w;
    Bs[cc + 4][rr] = b1.x; Bs[cc + 5][rr] = b1.y; Bs[cc + 6][rr] = b1.z; Bs[cc + 7][rr] = b1.w;
    __syncthreads();
#pragma unroll
    for (int kk = 0; kk < 32; ++kk) {
      float4 a4 = *(const float4*)&As[kk][tm * 4];
      float4 b4 = *(const float4*)&Bs[kk][tn * 4];
      float aa[4] = {a4.x, a4.y, a4.z, a4.w};
      float bb[4] = {b4.x, b4.y, b4.z, b4.w};
#pragma unroll
      for (int i = 0; i < 4; ++i)
#pragma unroll
        for (int j = 0; j < 4; ++j) acc[i][j] += aa[i] * bb[j];
    }
    __syncthreads();
  }
#pragma unroll
  for (int i = 0; i < 4; ++i) {
    int mr = m0 + tm * 4 + i;
#pragma unroll
    for (int j = 0; j < 4; ++j) {
      int nc = n0 + tn * 4 + j;
      if (nc < N) C[(size_t)mr * N + nc] = acc[i][j];
    }
  }
}

// ---------------- K3a: rope cos/sin table [t][j] ----------------
__global__ __launch_bounds__(256) void k_rope_table(float2* __restrict__ tab) {
  int idx = blockIdx.x * 256 + threadIdx.x;  // 1024*32
  int t = idx >> 5, j = idx & 31;
  float invf = (float)exp2(-(double)j * (13.287712379549449 / 32.0));  // 10000^(-j/32)
  float ang = (float)t * invf;                                         // fp32, matches ref
  double s, c;
  sincos((double)ang, &s, &c);
  tab[idx] = make_float2((float)c, (float)s);
}

// ---------------- K3b: rope(q,k), rmsnorm(k), rmsnorm(v), alpha, mix; transpose ----------------
__global__ __launch_bounds__(256) void k_postproc(
    const float* __restrict__ q_in, const float* __restrict__ k_in, const float* __restrict__ v_in,
    const float* __restrict__ a_pre, const float* __restrict__ m_pre,
    const float* __restrict__ ab, const float* __restrict__ mb,
    const float* __restrict__ kn_w, const float* __restrict__ vn_w,
    const float2* __restrict__ tab,
    float* __restrict__ qh, float* __restrict__ kh, float* __restrict__ vh,
    float* __restrict__ av, float* __restrict__ mv) {
  int wid = blockIdx.x * 4 + (threadIdx.x >> 6);  // one wave per (b,t,h)
  int lane = threadIdx.x & 63;
  int b = wid >> 13;
  int rem = wid & 8191;
  int t = rem >> 3;
  int h = rem & 7;
  size_t src = (size_t)(b * SEQT + t) * HIDN + h * HDIM + lane;
  float qv = q_in[src], kv = k_in[src], vv = v_in[src];
  float2 cs = tab[t * 32 + (lane & 31)];
  float qpart = __shfl_xor(qv, 32, 64);
  float kpart = __shfl_xor(kv, 32, 64);
  float qr = (lane < 32) ? (qv * cs.x - qpart * cs.y) : (qpart * cs.y + qv * cs.x);
  float kr = (lane < 32) ? (kv * cs.x - kpart * cs.y) : (kpart * cs.y + kv * cs.x);
  float kss = wred(kr * kr);
  float kn = kr * rsqrtf(kss * (1.0f / HDIM) + 1e-5f) * kn_w[lane];
  float vss = wred(vv * vv);
  float vn = vv * rsqrtf(vss * (1.0f / HDIM) + 1e-5f) * vn_w[lane];
  size_t dst = ((size_t)(b * NHD + h) * SEQT + t) * HDIM + lane;
  qh[dst] = qr;
  kh[dst] = kn;
  vh[dst] = vn;
  if (lane < 4) {
    int col = h * 4 + lane;
    float pa = a_pre[(size_t)(b * SEQT + t) * 32 + col] + ab[col];
    float al = 1.0f / (1.0f + expf(-pa));
    al = fminf(fmaxf(al, 1e-4f), 0.9995f);
    float pm = m_pre[(size_t)(b * SEQT + t) * 32 + col] + mb[col];
    float mx = pm;
    mx = fmaxf(mx, __shfl_xor(mx, 1, 64));
    mx = fmaxf(mx, __shfl_xor(mx, 2, 64));
    float e = expf(pm - mx);
    float sum = e;
    sum += __shfl_xor(sum, 1, 64);
    sum += __shfl_xor(sum, 2, 64);
    size_t adst = ((size_t)(b * NHD + h) * KTSN + lane) * SEQT + t;
    av[adst] = al;
    mv[adst] = e / sum;
  }
}

// ---------------- K4: sequential scan, ONE WAVE per (b,h,kt) cell ----------------
// h-state = 64 NAMED scalar floats (r6-proven to promote; vectors/asm demote).
// 4-buffer LDS pipeline: iter T reads kq[T&3] (written at T-2), writes
// kq[(T+2)&3]. Global prefetch distance 4 via named rotating stages.
// Norm allreduce: 4 DPP rors + 4 readlanes (no ds_bpermute on the g-chain).
#define G16(X) \
  X(0) X(1) X(2) X(3) X(4) X(5) X(6) X(7) \
  X(8) X(9) X(10) X(11) X(12) X(13) X(14) X(15)

#define DECLH(g) \
  float h##g##_0 = 0.f, h##g##_1 = 0.f, h##g##_2 = 0.f, h##g##_3 = 0.f;

#define UPDH(g)                                   \
  {                                               \
    float4 kf = kvec[g];                          \
    h##g##_0 = fmaf(h##g##_0, ag, kf.x * vem);    \
    h##g##_1 = fmaf(h##g##_1, ag, kf.y * vem);    \
    h##g##_2 = fmaf(h##g##_2, ag, kf.z * vem);    \
    h##g##_3 = fmaf(h##g##_3, ag, kf.w * vem);    \
    sq0 = fmaf(h##g##_0, h##g##_0, sq0);          \
    sq1 = fmaf(h##g##_1, h##g##_1, sq1);          \
    sq2 = fmaf(h##g##_2, h##g##_2, sq2);          \
    sq3 = fmaf(h##g##_3, h##g##_3, sq3);          \
  }

#define YUPH(g)                                   \
  {                                               \
    float4 qf = qvec[g];                          \
    y0 = fmaf(qf.x, h##g##_0, y0);                \
    y1 = fmaf(qf.y, h##g##_1, y1);                \
    y2 = fmaf(qf.z, h##g##_2, y2);                \
    y3 = fmaf(qf.w, h##g##_3, y3);                \
  }

#define SCAN_BODY(T, RP, WP)                                              \
  {                                                                       \
    int t4 = (T) + 4;                                                     \
    if (t4 > SEQT - 1) t4 = SEQT - 1;                                     \
    float kN = kp[(size_t)t4 * HDIM + lane];                              \
    float qN = qp[(size_t)t4 * HDIM + lane];                              \
    float vN = vp[(size_t)t4 * HDIM + lane];                              \
    float aN = ap[t4];                                                    \
    float mxN = mp[t4];                                                   \
    float mN = (float)mk[t4];                                             \
    const float4* kvec = (const float4*)&kq[RP][0][0];                    \
    const float4* qvec = (const float4*)&kq[RP][1][0];                    \
    float ag = aC * gprev;   /* deferred norm scale folded into alpha */  \
    float vem = vC * mC;     /* mask folded into v */                     \
    float sq0 = 0.f, sq1 = 0.f, sq2 = 0.f, sq3 = 0.f;                     \
    G16(UPDH)                                                             \
    float sq = wsum64_fast(((sq0 + sq1) + (sq2 + sq3)));                  \
    float y0 = 0.f, y1 = 0.f, y2 = 0.f, y3 = 0.f;                         \
    G16(YUPH)                                                             \
    float g = fminf(16.0f / (sqrtf(sq) + 1e-6f), 1.0f); /* c=sqrt(64)*2 */\
    ypo[(size_t)(T) * HIDN] = (mxC * g) * ((y0 + y1) + (y2 + y3));        \
    gprev = g;                                                            \
    kq[WP][0][lane] = kA;   /* data for step T+2 */                       \
    kq[WP][1][lane] = qA;                                                 \
    kA = kB; qA = qB; kB = kN; qB = qN;                                   \
    vC = vD; vD = vE; vE = vF; vF = vN;                                   \
    aC = aD; aD = aE; aE = aF; aF = aN;                                   \
    mxC = mxD; mxD = mxE; mxE = mxF; mxF = mxN;                           \
    mC = mD; mD = mE; mE = mF; mF = mN;                                   \
  }

__global__ __launch_bounds__(64, 1) __attribute__((amdgpu_waves_per_eu(1)))
void k_scan(
    const float* __restrict__ qh, const float* __restrict__ kh, const float* __restrict__ vh,
    const float* __restrict__ av, const float* __restrict__ mv, const int* __restrict__ mask,
    float* __restrict__ y0p, float* __restrict__ y1p, float* __restrict__ y2p,
    float* __restrict__ y3p) {
  int c = blockIdx.x;  // (b*NH+h)*KTS + kt
  int kt = c & 3;
  int bh = c >> 2;
  int b = bh >> 3;
  int h = bh & 7;
  int lane = threadIdx.x;  // 0..63, = e

  const float* kp = kh + (size_t)bh * SEQT * HDIM;
  const float* qp = qh + (size_t)bh * SEQT * HDIM;
  const float* vp = vh + (size_t)bh * SEQT * HDIM;
  const float* ap = av + (size_t)c * SEQT;
  const float* mp = mv + (size_t)c * SEQT;
  const int* mk = mask + (size_t)b * SEQT;
  float* ysel = (kt == 0) ? y0p : (kt == 1) ? y1p : (kt == 2) ? y2p : y3p;
  float* ypo = ysel + (size_t)(b * SEQT) * HIDN + h * HDIM + lane;

  __shared__ __align__(16) float kq[4][2][64];  // [buf][k|q][d] - 2KB

  G16(DECLH)  // h0_0..h15_3 = 64 named floats, all zero
  float gprev = 1.0f;

  // prologue (single wave, no barriers): buffers 0,1 <- steps 0,1;
  // register stages: kA/qA=step2, kB/qB=step3; v/a/mx/m 4-deep (steps 0..3).
  kq[0][0][lane] = kp[lane];
  kq[0][1][lane] = qp[lane];
  kq[1][0][lane] = kp[HDIM + lane];
  kq[1][1][lane] = qp[HDIM + lane];
  float kA = kp[2 * HDIM + lane], qA = qp[2 * HDIM + lane];
  float kB = kp[3 * HDIM + lane], qB = qp[3 * HDIM + lane];
  float vC = vp[lane], vD = vp[HDIM + lane], vE = vp[2 * HDIM + lane], vF = vp[3 * HDIM + lane];
  float aC = ap[0], aD = ap[1], aE = ap[2], aF = ap[3];
  float mxC = mp[0], mxD = mp[1], mxE = mp[2], mxF = mp[3];
  float mC = (float)mk[0], mD = (float)mk[1], mE = (float)mk[2], mF = (float)mk[3];

  for (int t = 0; t < SEQT; t += 4) {
    SCAN_BODY(t + 0, 0, 2)
    SCAN_BODY(t + 1, 1, 3)
    SCAN_BODY(t + 2, 2, 0)
    SCAN_BODY(t + 3, 3, 1)
  }
}

// ---------------- K5: r = x + (sum_kt y) @ oW^T + ob ----------------
__global__ __launch_bounds__(256) void k_gemm_out(
    const float* __restrict__ y0, const float* __restrict__ y1,
    const float* __restrict__ y2, const float* __restrict__ y3,
    const float* __restrict__ oW, const float* __restrict__ ob,
    const float* __restrict__ x, float* __restrict__ r) {
  __shared__ __align__(16) float As[32][68];
  __shared__ __align__(16) float Bs[32][68];
  int tid = threadIdx.x;
  int m0 = blockIdx.x * 64, n0 = blockIdx.y * 64;
  int tm = tid >> 4, tn = tid & 15;
  float acc[4][4] = {};
  int rr = tid >> 2, cc = (tid & 3) * 8;
  for (int k0 = 0; k0 < HIDN; k0 += 32) {
    size_t aoff = (size_t)(m0 + rr) * HIDN + k0 + cc;
#pragma unroll
    for (int half = 0; half < 2; ++half) {
      size_t sh = aoff + half * 4;
      float4 p0 = *(const float4*)(y0 + sh);
      float4 p1 = *(const float4*)(y1 + sh);
      float4 p2 = *(const float4*)(y2 + sh);
      float4 p3 = *(const float4*)(y3 + sh);
      int cbase = cc + half * 4;
      As[cbase + 0][rr] = p0.x + p1.x + p2.x + p3.x;
      As[cbase + 1][rr] = p0.y + p1.y + p2.y + p3.y;
      As[cbase + 2][rr] = p0.z + p1.z + p2.z + p3.z;
      As[cbase + 3][rr] = p0.w + p1.w + p2.w + p3.w;
    }
    const float* s1 = oW + (size_t)(n0 + rr) * HIDN + k0 + cc;
    float4 b0 = *(const float4*)s1;
    float4 b1 = *(const float4*)(s1 + 4);
    Bs[cc + 0][rr] = b0.x; Bs[cc + 1][rr] = b0.y; Bs[cc + 2][rr] = b0.z; Bs[cc + 3][rr] = b0.w;
    Bs[cc + 4][rr] = b1.x; Bs[cc + 5][rr] = b1.y; Bs[cc + 6][rr] = b1.z; Bs[cc + 7][rr] = b1.w;
    __syncthreads();
#pragma unroll
    for (int kk = 0; kk < 32; ++kk) {
      float4 a4 = *(const float4*)&As[kk][tm * 4];
      float4 b4 = *(const float4*)&Bs[kk][tn * 4];
      float aa[4] = {a4.x, a4.y, a4.z, a4.w};
      float bb[4] = {b4.x, b4.y, b4.z, b4.w};
#pragma unroll
      for (int i = 0; i < 4; ++i)
#pragma unroll
        for (int j = 0; j < 4; ++j) acc[i][j] += aa[i] * bb[j];
    }
    __syncthreads();
  }
#pragma unroll
  for (int i = 0; i < 4; ++i) {
    int mr = m0 + tm * 4 + i;
#pragma unroll
    for (int j = 0; j < 4; ++j) {
      int nc = n0 + tn * 4 + j;
      r[(size_t)mr * HIDN + nc] = x[(size_t)mr * HIDN + nc] + acc[i][j] + ob[nc];
    }
  }
}

// ---------------- K6: LayerNorm -> out ----------------
__global__ __launch_bounds__(256) void k_layernorm(
    const float* __restrict__ r, const float* __restrict__ w, const float* __restrict__ bb,
    float* __restrict__ out) {
  int m = blockIdx.x;
  int tid = threadIdx.x;
  const float* row = r + (size_t)m * HIDN;
  float2 v = *(const float2*)(row + tid * 2);
  float s = wred(v.x + v.y);
  float ss = wred(v.x * v.x + v.y * v.y);
  __shared__ float r1[4], r2[4];
  int lane = tid & 63, wv = tid >> 6;
  if (lane == 0) {
    r1[wv] = s;
    r2[wv] = ss;
  }
  __syncthreads();
  float S = r1[0] + r1[1] + r1[2] + r1[3];
  float SS = r2[0] + r2[1] + r2[2] + r2[3];
  float mu = S * (1.0f / HIDN);
  float var = SS * (1.0f / HIDN) - mu * mu;
  float inv = rsqrtf(var + 1e-5f);
  float2 w2 = *(const float2*)(w + tid * 2);
  float2 b2 = *(const float2*)(bb + tid * 2);
  float2 o;
  o.x = (v.x - mu) * inv * w2.x + b2.x;
  o.y = (v.y - mu) * inv * w2.y + b2.y;
  *(float2*)(out + (size_t)m * HIDN + tid * 2) = o;
}

// ---------------- launch ----------------
extern "C" void kernel_launch(void* const* d_in, const int* in_sizes, int n_in,
                              void* d_out, int out_size, void* d_ws, size_t ws_size,
                              hipStream_t stream) {
  const float* x = (const float*)d_in[0];
  const float* in_w = (const float*)d_in[1];
  const float* qW = (const float*)d_in[2];
  const float* kW = (const float*)d_in[3];
  const float* vW = (const float*)d_in[4];
  const float* aW = (const float*)d_in[5];
  const float* ab = (const float*)d_in[6];
  const float* mW = (const float*)d_in[7];
  const float* mb = (const float*)d_in[8];
  const float* oW = (const float*)d_in[9];
  const float* ob = (const float*)d_in[10];
  const float* kn_w = (const float*)d_in[11];
  const float* vn_w = (const float*)d_in[12];
  const float* ln_w = (const float*)d_in[13];
  const float* ln_b = (const float*)d_in[14];
  const int* mask = (const int*)d_in[15];

  float* ws = (float*)d_ws;
  // Layout (floats). No live overlap:
  //   xn    [0        , 1048576 )  dead after 5 GEMMs -> reused as rr
  //   qb    [1048576  , 2097152 )  dead after postproc -> reused as y0
  //   kb    [2097152  , 3145728 )  dead after postproc -> reused as y1
  //   vb    [3145728  , 4194304 )  dead after postproc -> reused as y2
  //   apre  [4194304  , 4259840 )
  //   mpre  [4259840  , 4325376 )
  //   tab   [4325376  , 4390912 )
  //   qh    [4390912  , 5439488 )
  //   kh    [5439488  , 6488064 )
  //   vh    [6488064  , 7536640 )
  //   avv   [7536640  , 7602176 )
  //   mvv   [7602176  , 7667712 )
  //   y3    [7667712  , 8716288 )   total ~34.9 MB
  float* xn = ws + 0;
  float* qb = ws + 1048576;
  float* kb = ws + 2097152;
  float* vb = ws + 3145728;
  float* apre = ws + 4194304;
  float* mpre = ws + 4259840;
  float2* tab = (float2*)(ws + 4325376);
  float* qh = ws + 4390912;
  float* kh = ws + 5439488;
  float* vh = ws + 6488064;
  float* avv = ws + 7536640;
  float* mvv = ws + 7602176;
  float* y3 = ws + 7667712;
  float* y0 = qb;
  float* y1 = kb;
  float* y2 = vb;
  float* rr = xn;

  k_rmsnorm_in<<<NTOK, 256, 0, stream>>>(x, in_w, xn);
  k_rope_table<<<128, 256, 0, stream>>>(tab);
  dim3 gBig(32, 8);
  k_gemm_nt<<<gBig, 256, 0, stream>>>(xn, qW, qb, 512);
  k_gemm_nt<<<gBig, 256, 0, stream>>>(xn, kW, kb, 512);
  k_gemm_nt<<<gBig, 256, 0, stream>>>(xn, vW, vb, 512);
  dim3 gSmall(32, 1);
  k_gemm_nt<<<gSmall, 256, 0, stream>>>(xn, aW, apre, 32);
  k_gemm_nt<<<gSmall, 256, 0, stream>>>(xn, mW, mpre, 32);
  k_postproc<<<4096, 256, 0, stream>>>(qb, kb, vb, apre, mpre, ab, mb, kn_w, vn_w, tab,
                                       qh, kh, vh, avv, mvv);
  k_scan<<<64, 64, 0, stream>>>(qh, kh, vh, avv, mvv, mask, y0, y1, y2, y3);
  k_gemm_out<<<gBig, 256, 0, stream>>>(y0, y1, y2, y3, oW, ob, x, rr);
  k_layernorm<<<NTOK, 256, 0, stream>>>(rr, ln_w, ln_b, (float*)d_out);
  (void)in_sizes; (void)n_in; (void)out_size; (void)ws_size;
}

// Round 9
// 954.261 us; speedup vs baseline: 1.4130x; 1.3986x over previous
//
#include <hip/hip_runtime.h>
#include <math.h>

#define SEQT 1024
#define NTOK 2048
#define HIDN 512
#define NHD 8
#define HDIM 64
#define KTSN 4

__device__ __forceinline__ float wred(float v) {
#pragma unroll
  for (int off = 32; off; off >>= 1) v += __shfl_xor(v, off, 64);
  return v;
}

// rotation-allreduce within rows of 16 via DPP (VALU-speed)
template <int CTRL>
__device__ __forceinline__ float rra(float v) {
  return v + __int_as_float(__builtin_amdgcn_update_dpp(
                 0, __float_as_int(v), CTRL, 0xf, 0xf, true));
}
__device__ __forceinline__ float rlane(float v, int l) {
  return __int_as_float(__builtin_amdgcn_readlane(__float_as_int(v), l));
}
// full-wave sum: 4 DPP row_rors (row sums) + 4 readlanes + adds.
// Entirely VALU/SALU: keeps the serial g-chain off the LDS pipe.
__device__ __forceinline__ float wsum64_fast(float v) {
  v = rra<0x121>(v);  // row_ror:1
  v = rra<0x122>(v);  // row_ror:2
  v = rra<0x124>(v);  // row_ror:4
  v = rra<0x128>(v);  // row_ror:8  -> each lane has its 16-lane row sum
  return (rlane(v, 0) + rlane(v, 16)) + (rlane(v, 32) + rlane(v, 48));
}

// ---------------- K1: input RMSNorm (one block per row) ----------------
__global__ __launch_bounds__(256) void k_rmsnorm_in(
    const float* __restrict__ x, const float* __restrict__ w, float* __restrict__ xn) {
  int m = blockIdx.x;
  int tid = threadIdx.x;
  const float* row = x + (size_t)m * HIDN;
  float2 v = *(const float2*)(row + tid * 2);
  float ss = wred(v.x * v.x + v.y * v.y);
  __shared__ float red[4];
  int lane = tid & 63, wv = tid >> 6;
  if (lane == 0) red[wv] = ss;
  __syncthreads();
  float tot = red[0] + red[1] + red[2] + red[3];
  float inv = rsqrtf(tot * (1.0f / HIDN) + 1e-5f);
  float2 wv2 = *(const float2*)(w + tid * 2);
  float2 o;
  o.x = v.x * inv * wv2.x;
  o.y = v.y * inv * wv2.y;
  *(float2*)(xn + (size_t)m * HIDN + tid * 2) = o;
}

// ---------------- K2: C[m][n] = sum_k A[m][k]*B[n][k]  (M=2048, K=512) ----------------
__global__ __launch_bounds__(256) void k_gemm_nt(
    const float* __restrict__ A, const float* __restrict__ B, float* __restrict__ C, int N) {
  __shared__ __align__(16) float As[32][68];
  __shared__ __align__(16) float Bs[32][68];
  int tid = threadIdx.x;
  int m0 = blockIdx.x * 64, n0 = blockIdx.y * 64;
  int tm = tid >> 4, tn = tid & 15;
  float acc[4][4] = {};
  int rr = tid >> 2, cc = (tid & 3) * 8;
  for (int k0 = 0; k0 < HIDN; k0 += 32) {
    const float* s0 = A + (size_t)(m0 + rr) * HIDN + k0 + cc;
    float4 a0 = *(const float4*)s0;
    float4 a1 = *(const float4*)(s0 + 4);
    As[cc + 0][rr] = a0.x; As[cc + 1][rr] = a0.y; As[cc + 2][rr] = a0.z; As[cc + 3][rr] = a0.w;
    As[cc + 4][rr] = a1.x; As[cc + 5][rr] = a1.y; As[cc + 6][rr] = a1.z; As[cc + 7][rr] = a1.w;
    int bn = n0 + rr;
    float4 b0 = make_float4(0.f, 0.f, 0.f, 0.f), b1 = make_float4(0.f, 0.f, 0.f, 0.f);
    if (bn < N) {
      const float* s1 = B + (size_t)bn * HIDN + k0 + cc;
      b0 = *(const float4*)s1;
      b1 = *(const float4*)(s1 + 4);
    }
    Bs[cc + 0][rr] = b0.x; Bs[cc + 1][rr] = b0.y; Bs[cc + 2][rr] = b0.z; Bs[cc + 3][rr] = b0.w;
    Bs[cc + 4][rr] = b1.x; Bs[cc + 5][rr] = b1.y; Bs[cc + 6][rr] = b1.z; Bs[cc + 7][rr] = b1.w;
    __syncthreads();
#pragma unroll
    for (int kk = 0; kk < 32; ++kk) {
      float4 a4 = *(const float4*)&As[kk][tm * 4];
      float4 b4 = *(const float4*)&Bs[kk][tn * 4];
      float aa[4] = {a4.x, a4.y, a4.z, a4.w};
      float bb[4] = {b4.x, b4.y, b4.z, b4.w};
#pragma unroll
      for (int i = 0; i < 4; ++i)
#pragma unroll
        for (int j = 0; j < 4; ++j) acc[i][j] += aa[i] * bb[j];
    }
    __syncthreads();
  }
#pragma unroll
  for (int i = 0; i < 4; ++i) {
    int mr = m0 + tm * 4 + i;
#pragma unroll
    for (int j = 0; j < 4; ++j) {
      int nc = n0 + tn * 4 + j;
      if (nc < N) C[(size_t)mr * N + nc] = acc[i][j];
    }
  }
}

// ---------------- K3a: rope cos/sin table [t][j] ----------------
__global__ __launch_bounds__(256) void k_rope_table(float2* __restrict__ tab) {
  int idx = blockIdx.x * 256 + threadIdx.x;  // 1024*32
  int t = idx >> 5, j = idx & 31;
  float invf = (float)exp2(-(double)j * (13.287712379549449 / 32.0));  // 10000^(-j/32)
  float ang = (float)t * invf;                                         // fp32, matches ref
  double s, c;
  sincos((double)ang, &s, &c);
  tab[idx] = make_float2((float)c, (float)s);
}

// ---------------- K3b: rope(q,k), rmsnorm(k), rmsnorm(v), alpha, mix; transpose ----------------
__global__ __launch_bounds__(256) void k_postproc(
    const float* __restrict__ q_in, const float* __restrict__ k_in, const float* __restrict__ v_in,
    const float* __restrict__ a_pre, const float* __restrict__ m_pre,
    const float* __restrict__ ab, const float* __restrict__ mb,
    const float* __restrict__ kn_w, const float* __restrict__ vn_w,
    const float2* __restrict__ tab,
    float* __restrict__ qh, float* __restrict__ kh, float* __restrict__ vh,
    float* __restrict__ av, float* __restrict__ mv) {
  int wid = blockIdx.x * 4 + (threadIdx.x >> 6);  // one wave per (b,t,h)
  int lane = threadIdx.x & 63;
  int b = wid >> 13;
  int rem = wid & 8191;
  int t = rem >> 3;
  int h = rem & 7;
  size_t src = (size_t)(b * SEQT + t) * HIDN + h * HDIM + lane;
  float qv = q_in[src], kv = k_in[src], vv = v_in[src];
  float2 cs = tab[t * 32 + (lane & 31)];
  float qpart = __shfl_xor(qv, 32, 64);
  float kpart = __shfl_xor(kv, 32, 64);
  float qr = (lane < 32) ? (qv * cs.x - qpart * cs.y) : (qpart * cs.y + qv * cs.x);
  float kr = (lane < 32) ? (kv * cs.x - kpart * cs.y) : (kpart * cs.y + kv * cs.x);
  float kss = wred(kr * kr);
  float kn = kr * rsqrtf(kss * (1.0f / HDIM) + 1e-5f) * kn_w[lane];
  float vss = wred(vv * vv);
  float vn = vv * rsqrtf(vss * (1.0f / HDIM) + 1e-5f) * vn_w[lane];
  size_t dst = ((size_t)(b * NHD + h) * SEQT + t) * HDIM + lane;
  qh[dst] = qr;
  kh[dst] = kn;
  vh[dst] = vn;
  if (lane < 4) {
    int col = h * 4 + lane;
    float pa = a_pre[(size_t)(b * SEQT + t) * 32 + col] + ab[col];
    float al = 1.0f / (1.0f + expf(-pa));
    al = fminf(fmaxf(al, 1e-4f), 0.9995f);
    float pm = m_pre[(size_t)(b * SEQT + t) * 32 + col] + mb[col];
    float mx = pm;
    mx = fmaxf(mx, __shfl_xor(mx, 1, 64));
    mx = fmaxf(mx, __shfl_xor(mx, 2, 64));
    float e = expf(pm - mx);
    float sum = e;
    sum += __shfl_xor(sum, 1, 64);
    sum += __shfl_xor(sum, 2, 64);
    size_t adst = ((size_t)(b * NHD + h) * KTSN + lane) * SEQT + t;
    av[adst] = al;
    mv[adst] = e / sum;
  }
}

// ---------------- K4: sequential scan, ONE WAVE per (b,h,kt) cell ----------------
// h-state = 64 NAMED scalar floats (r6-proven to promote; vectors/asm demote).
// LDS reads are BATCHED into named float4 groups (kf0..15, qf0..15) so the
// compiler emits 16 ds_read_b128 + ONE lgkmcnt wait per group instead of
// interleaved load/wait/use chains (the r6/r8 stall). The qf batch is issued
// before the norm reduction so the DPP+rsqrt chain hides its latency.
#define G16(X) \
  X(0) X(1) X(2) X(3) X(4) X(5) X(6) X(7) \
  X(8) X(9) X(10) X(11) X(12) X(13) X(14) X(15)

#define DECLH(g) \
  float h##g##_0 = 0.f, h##g##_1 = 0.f, h##g##_2 = 0.f, h##g##_3 = 0.f;

#define LOADKF(g) float4 kf##g = kvec[g];
#define LOADQF(g) float4 qf##g = qvec[g];

#define UPDH(g)                                     \
  {                                                 \
    h##g##_0 = fmaf(h##g##_0, ag, kf##g.x * vem);   \
    h##g##_1 = fmaf(h##g##_1, ag, kf##g.y * vem);   \
    h##g##_2 = fmaf(h##g##_2, ag, kf##g.z * vem);   \
    h##g##_3 = fmaf(h##g##_3, ag, kf##g.w * vem);   \
    sq0 = fmaf(h##g##_0, h##g##_0, sq0);            \
    sq1 = fmaf(h##g##_1, h##g##_1, sq1);            \
    sq2 = fmaf(h##g##_2, h##g##_2, sq2);            \
    sq3 = fmaf(h##g##_3, h##g##_3, sq3);            \
  }

#define YUPH(g)                                     \
  {                                                 \
    y0 = fmaf(qf##g.x, h##g##_0, y0);               \
    y1 = fmaf(qf##g.y, h##g##_1, y1);               \
    y2 = fmaf(qf##g.z, h##g##_2, y2);               \
    y3 = fmaf(qf##g.w, h##g##_3, y3);               \
  }

__global__ __launch_bounds__(64, 1) __attribute__((amdgpu_waves_per_eu(1)))
void k_scan(
    const float* __restrict__ qh, const float* __restrict__ kh, const float* __restrict__ vh,
    const float* __restrict__ av, const float* __restrict__ mv, const int* __restrict__ mask,
    float* __restrict__ y0p, float* __restrict__ y1p, float* __restrict__ y2p,
    float* __restrict__ y3p) {
  int c = blockIdx.x;  // (b*NH+h)*KTS + kt
  int kt = c & 3;
  int bh = c >> 2;
  int b = bh >> 3;
  int h = bh & 7;
  int lane = threadIdx.x;  // 0..63, = e

  const float* kp = kh + (size_t)bh * SEQT * HDIM;
  const float* qp = qh + (size_t)bh * SEQT * HDIM;
  const float* vp = vh + (size_t)bh * SEQT * HDIM;
  const float* ap = av + (size_t)c * SEQT;
  const float* mp = mv + (size_t)c * SEQT;
  const int* mk = mask + (size_t)b * SEQT;
  float* ysel = (kt == 0) ? y0p : (kt == 1) ? y1p : (kt == 2) ? y2p : y3p;
  float* ypo = ysel + (size_t)(b * SEQT) * HIDN + h * HDIM + lane;

  __shared__ __align__(16) float kq[2][2][64];  // [parity][k|q][d] - 1KB

  G16(DECLH)  // h0_0..h15_3 = 64 named floats, all zero
  float gprev = 1.0f;

  // prologue (single wave, no barriers): stage t=0 into parity 0
  kq[0][0][lane] = kp[lane];
  kq[0][1][lane] = qp[lane];
  float vC = vp[lane];
  float aC = ap[0], mxC = mp[0];
  float mC = (float)mk[0];

  for (int t = 0; t < SEQT; ++t) {
    // global prefetch t+1 (consumed by the ds_write at iteration end)
    int tn = t + 1;
    if (tn > SEQT - 1) tn = SEQT - 1;
    float kpre = kp[(size_t)tn * HDIM + lane];
    float qpre = qp[(size_t)tn * HDIM + lane];
    float vpre = vp[(size_t)tn * HDIM + lane];
    float aN = ap[tn];
    float mxN = mp[tn];
    float mN = (float)mk[tn];

    const int P = t & 1;
    const float4* kvec = (const float4*)&kq[P][0][0];
    const float4* qvec = (const float4*)&kq[P][1][0];

    G16(LOADKF)  // 16 ds_read_b128, one wait
    float ag = aC * gprev;  // deferred norm scale folded into alpha
    float vem = vC * mC;    // mask folded into v
    float sq0 = 0.f, sq1 = 0.f, sq2 = 0.f, sq3 = 0.f;
    G16(UPDH)    // 128 FMA on registers
    G16(LOADQF)  // issue q batch; latency hidden under the norm chain below
    float sq = wsum64_fast(((sq0 + sq1) + (sq2 + sq3)));
    float g = fminf(16.0f * rsqrtf(sq), 1.0f);  // c=sqrt(64)*2; sq=0 -> min(inf,1)=1
    float y0 = 0.f, y1 = 0.f, y2 = 0.f, y3 = 0.f;
    G16(YUPH)    // 64 FMA
    ypo[(size_t)t * HIDN] = (mxC * g) * ((y0 + y1) + (y2 + y3));
    gprev = g;

    // stage t+1 into the other parity buffer
    kq[P ^ 1][0][lane] = kpre;
    kq[P ^ 1][1][lane] = qpre;
    vC = vpre;
    aC = aN;
    mxC = mxN;
    mC = mN;
  }
}

// ---------------- K5: r = x + (sum_kt y) @ oW^T + ob ----------------
__global__ __launch_bounds__(256) void k_gemm_out(
    const float* __restrict__ y0, const float* __restrict__ y1,
    const float* __restrict__ y2, const float* __restrict__ y3,
    const float* __restrict__ oW, const float* __restrict__ ob,
    const float* __restrict__ x, float* __restrict__ r) {
  __shared__ __align__(16) float As[32][68];
  __shared__ __align__(16) float Bs[32][68];
  int tid = threadIdx.x;
  int m0 = blockIdx.x * 64, n0 = blockIdx.y * 64;
  int tm = tid >> 4, tn = tid & 15;
  float acc[4][4] = {};
  int rr = tid >> 2, cc = (tid & 3) * 8;
  for (int k0 = 0; k0 < HIDN; k0 += 32) {
    size_t aoff = (size_t)(m0 + rr) * HIDN + k0 + cc;
#pragma unroll
    for (int half = 0; half < 2; ++half) {
      size_t sh = aoff + half * 4;
      float4 p0 = *(const float4*)(y0 + sh);
      float4 p1 = *(const float4*)(y1 + sh);
      float4 p2 = *(const float4*)(y2 + sh);
      float4 p3 = *(const float4*)(y3 + sh);
      int cbase = cc + half * 4;
      As[cbase + 0][rr] = p0.x + p1.x + p2.x + p3.x;
      As[cbase + 1][rr] = p0.y + p1.y + p2.y + p3.y;
      As[cbase + 2][rr] = p0.z + p1.z + p2.z + p3.z;
      As[cbase + 3][rr] = p0.w + p1.w + p2.w + p3.w;
    }
    const float* s1 = oW + (size_t)(n0 + rr) * HIDN + k0 + cc;
    float4 b0 = *(const float4*)s1;
    float4 b1 = *(const float4*)(s1 + 4);
    Bs[cc + 0][rr] = b0.x; Bs[cc + 1][rr] = b0.y; Bs[cc + 2][rr] = b0.z; Bs[cc + 3][rr] = b0.w;
    Bs[cc + 4][rr] = b1.x; Bs[cc + 5][rr] = b1.y; Bs[cc + 6][rr] = b1.z; Bs[cc + 7][rr] = b1.w;
    __syncthreads();
#pragma unroll
    for (int kk = 0; kk < 32; ++kk) {
      float4 a4 = *(const float4*)&As[kk][tm * 4];
      float4 b4 = *(const float4*)&Bs[kk][tn * 4];
      float aa[4] = {a4.x, a4.y, a4.z, a4.w};
      float bb[4] = {b4.x, b4.y, b4.z, b4.w};
#pragma unroll
      for (int i = 0; i < 4; ++i)
#pragma unroll
        for (int j = 0; j < 4; ++j) acc[i][j] += aa[i] * bb[j];
    }
    __syncthreads();
  }
#pragma unroll
  for (int i = 0; i < 4; ++i) {
    int mr = m0 + tm * 4 + i;
#pragma unroll
    for (int j = 0; j < 4; ++j) {
      int nc = n0 + tn * 4 + j;
      r[(size_t)mr * HIDN + nc] = x[(size_t)mr * HIDN + nc] + acc[i][j] + ob[nc];
    }
  }
}

// ---------------- K6: LayerNorm -> out ----------------
__global__ __launch_bounds__(256) void k_layernorm(
    const float* __restrict__ r, const float* __restrict__ w, const float* __restrict__ bb,
    float* __restrict__ out) {
  int m = blockIdx.x;
  int tid = threadIdx.x;
  const float* row = r + (size_t)m * HIDN;
  float2 v = *(const float2*)(row + tid * 2);
  float s = wred(v.x + v.y);
  float ss = wred(v.x * v.x + v.y * v.y);
  __shared__ float r1[4], r2[4];
  int lane = tid & 63, wv = tid >> 6;
  if (lane == 0) {
    r1[wv] = s;
    r2[wv] = ss;
  }
  __syncthreads();
  float S = r1[0] + r1[1] + r1[2] + r1[3];
  float SS = r2[0] + r2[1] + r2[2] + r2[3];
  float mu = S * (1.0f / HIDN);
  float var = SS * (1.0f / HIDN) - mu * mu;
  float inv = rsqrtf(var + 1e-5f);
  float2 w2 = *(const float2*)(w + tid * 2);
  float2 b2 = *(const float2*)(bb + tid * 2);
  float2 o;
  o.x = (v.x - mu) * inv * w2.x + b2.x;
  o.y = (v.y - mu) * inv * w2.y + b2.y;
  *(float2*)(out + (size_t)m * HIDN + tid * 2) = o;
}

// ---------------- launch ----------------
extern "C" void kernel_launch(void* const* d_in, const int* in_sizes, int n_in,
                              void* d_out, int out_size, void* d_ws, size_t ws_size,
                              hipStream_t stream) {
  const float* x = (const float*)d_in[0];
  const float* in_w = (const float*)d_in[1];
  const float* qW = (const float*)d_in[2];
  const float* kW = (const float*)d_in[3];
  const float* vW = (const float*)d_in[4];
  const float* aW = (const float*)d_in[5];
  const float* ab = (const float*)d_in[6];
  const float* mW = (const float*)d_in[7];
  const float* mb = (const float*)d_in[8];
  const float* oW = (const float*)d_in[9];
  const float* ob = (const float*)d_in[10];
  const float* kn_w = (const float*)d_in[11];
  const float* vn_w = (const float*)d_in[12];
  const float* ln_w = (const float*)d_in[13];
  const float* ln_b = (const float*)d_in[14];
  const int* mask = (const int*)d_in[15];

  float* ws = (float*)d_ws;
  // Layout (floats). No live overlap:
  //   xn    [0        , 1048576 )  dead after 5 GEMMs -> reused as rr
  //   qb    [1048576  , 2097152 )  dead after postproc -> reused as y0
  //   kb    [2097152  , 3145728 )  dead after postproc -> reused as y1
  //   vb    [3145728  , 4194304 )  dead after postproc -> reused as y2
  //   apre  [4194304  , 4259840 )
  //   mpre  [4259840  , 4325376 )
  //   tab   [4325376  , 4390912 )
  //   qh    [4390912  , 5439488 )
  //   kh    [5439488  , 6488064 )
  //   vh    [6488064  , 7536640 )
  //   avv   [7536640  , 7602176 )
  //   mvv   [7602176  , 7667712 )
  //   y3    [7667712  , 8716288 )   total ~34.9 MB
  float* xn = ws + 0;
  float* qb = ws + 1048576;
  float* kb = ws + 2097152;
  float* vb = ws + 3145728;
  float* apre = ws + 4194304;
  float* mpre = ws + 4259840;
  float2* tab = (float2*)(ws + 4325376);
  float* qh = ws + 4390912;
  float* kh = ws + 5439488;
  float* vh = ws + 6488064;
  float* avv = ws + 7536640;
  float* mvv = ws + 7602176;
  float* y3 = ws + 7667712;
  float* y0 = qb;
  float* y1 = kb;
  float* y2 = vb;
  float* rr = xn;

  k_rmsnorm_in<<<NTOK, 256, 0, stream>>>(x, in_w, xn);
  k_rope_table<<<128, 256, 0, stream>>>(tab);
  dim3 gBig(32, 8);
  k_gemm_nt<<<gBig, 256, 0, stream>>>(xn, qW, qb, 512);
  k_gemm_nt<<<gBig, 256, 0, stream>>>(xn, kW, kb, 512);
  k_gemm_nt<<<gBig, 256, 0, stream>>>(xn, vW, vb, 512);
  dim3 gSmall(32, 1);
  k_gemm_nt<<<gSmall, 256, 0, stream>>>(xn, aW, apre, 32);
  k_gemm_nt<<<gSmall, 256, 0, stream>>>(xn, mW, mpre, 32);
  k_postproc<<<4096, 256, 0, stream>>>(qb, kb, vb, apre, mpre, ab, mb, kn_w, vn_w, tab,
                                       qh, kh, vh, avv, mvv);
  k_scan<<<64, 64, 0, stream>>>(qh, kh, vh, avv, mvv, mask, y0, y1, y2, y3);
  k_gemm_out<<<gBig, 256, 0, stream>>>(y0, y1, y2, y3, oW, ob, x, rr);
  k_layernorm<<<NTOK, 256, 0, stream>>>(rr, ln_w, ln_b, (float*)d_out);
  (void)in_sizes; (void)n_in; (void)out_size; (void)ws_size;
}